// Round 7
// baseline (863.835 us; speedup 1.0000x reference)
//
#include <hip/hip_runtime.h>

// Multi-scale deformable attention (Deformable-DETR), forward. All shapes static:
// value: (2, 13294, 8, 32) f32 | loc: (2,13294,8,4,4,2) f32 | aw: (2,13294,8,4,4) f32
// out:   (2, 13294, 256) f32 (head-major channels)
//
// NOTE: XCD blockIdx swizzle is BANNED for this problem — it reproducibly
// trips the post-timing re-validation (R2, R5) despite being bijective.

#define BS 2
#define NH 8
#define DD 32
#define LL 4
#define PP 4
#define QQ 13294
#define KK 13294
#define LPG 8    // lanes per group; each lane holds 4 channels (f32x4)
#define GPB 32   // groups per 256-thread block
#define NWG 6647 // BS*NH*QQ / GPB, exact

typedef float f32x4 __attribute__((ext_vector_type(4)));

__global__ __launch_bounds__(256, 4) void msda_fwd_kernel(
    const f32x4* __restrict__ value4,  // (bs,K,nh,8) f32x4
    const f32x4* __restrict__ locv,    // (bs,Q,nh,L,P,2) viewed as f32x4[...][8]
    const f32x4* __restrict__ awv,     // (bs,Q,nh,L,P)   viewed as f32x4[...][4]
    f32x4*       __restrict__ out4)    // (bs,Q,nh,8) f32x4
{
    constexpr int Hs[4]     = {100, 50, 25, 13};
    constexpr int Ws[4]     = {100, 50, 25, 13};
    constexpr int starts[4] = {0, 10000, 12500, 13125};

    const int gid  = blockIdx.x * GPB + (threadIdx.x >> 3);  // (b,h,q)-ordered
    const int lane = threadIdx.x & (LPG - 1);

    const int q  = gid % QQ;
    const int bh = gid / QQ;
    const int h  = bh % NH;
    const int b  = bh / NH;

    const size_t lg = (size_t)(b * QQ + q) * NH + h;
    const f32x4* lp = locv + lg * 8;   // 16 samples * (x,y) = 8 f32x4
    const f32x4* wp = awv  + lg * 4;   // 16 weights       = 4 f32x4

    // f32x4 element for (b, key, h, lane): key stride = NH*DD/4 = 64 vectors
    const f32x4* vbase = value4 + ((size_t)b * KK * NH + h) * (DD / 4) + lane;

    // Hoist ALL loc/aw loads to entry: streamed once, issued as one batch so
    // no per-level stall on them.
    f32x4 lv[8], wv[4];
    #pragma unroll
    for (int i = 0; i < 8; ++i) lv[i] = __builtin_nontemporal_load(&lp[i]);
    #pragma unroll
    for (int i = 0; i < 4; ++i) wv[i] = __builtin_nontemporal_load(&wp[i]);

    f32x4 acc = {0.0f, 0.0f, 0.0f, 0.0f};

    #pragma unroll
    for (int l = 0; l < LL; ++l) {
        const int H = Hs[l], W = Ws[l];
        const float fH = (float)H, fW = (float)W;

        // Phase 2: all 4 samples' corner indices + weights (pure VALU)
        int   idx[PP][4];
        float wgt[PP][4];
        #pragma unroll
        for (int p = 0; p < PP; ++p) {
            const f32x4 lvp = lv[2 * l + (p >> 1)];
            const float lx = lvp[(p & 1) * 2 + 0];
            const float ly = lvp[(p & 1) * 2 + 1];
            const float w  = wv[l][p];

            // align_corners=False, padding zeros: x = loc_x*W - 0.5
            const float x = lx * fW - 0.5f;
            const float y = ly * fH - 0.5f;
            const float x0f = floorf(x), y0f = floorf(y);
            const float dx = x - x0f, dy = y - y0f;
            const int x0 = (int)x0f, y0 = (int)y0f;
            const int x1 = x0 + 1,  y1 = y0 + 1;

            const float mx0 = ((unsigned)x0 < (unsigned)W) ? 1.0f : 0.0f;
            const float mx1 = ((unsigned)x1 < (unsigned)W) ? 1.0f : 0.0f;
            const float my0 = ((unsigned)y0 < (unsigned)H) ? 1.0f : 0.0f;
            const float my1 = ((unsigned)y1 < (unsigned)H) ? 1.0f : 0.0f;

            const int cx0 = min(max(x0, 0), W - 1);
            const int cx1 = min(max(x1, 0), W - 1);
            const int cy0 = min(max(y0, 0), H - 1);
            const int cy1 = min(max(y1, 0), H - 1);

            const int r0 = starts[l] + cy0 * W;
            const int r1 = starts[l] + cy1 * W;
            idx[p][0] = r0 + cx0;  wgt[p][0] = (1.0f - dx) * (1.0f - dy) * w * mx0 * my0;
            idx[p][1] = r0 + cx1;  wgt[p][1] = dx * (1.0f - dy) * w * mx1 * my0;
            idx[p][2] = r1 + cx0;  wgt[p][2] = (1.0f - dx) * dy * w * mx0 * my1;
            idx[p][3] = r1 + cx1;  wgt[p][3] = dx * dy * w * mx1 * my1;
        }

        // Phase 3: issue all 16 corner gathers as one batch (16 misses in flight).
        f32x4 v[PP][4];
        #pragma unroll
        for (int p = 0; p < PP; ++p)
            #pragma unroll
            for (int c = 0; c < 4; ++c)
                v[p][c] = vbase[idx[p][c] * (NH * DD / 4)];

        // Pin the schedule: loads above may not sink past this point, FMAs below
        // may not hoist above it -> all 16 loads are in flight before any use.
        __builtin_amdgcn_sched_barrier(0);

        // Phase 4: 64 FMAs
        #pragma unroll
        for (int p = 0; p < PP; ++p)
            #pragma unroll
            for (int c = 0; c < 4; ++c) {
                acc.x = fmaf(wgt[p][c], v[p][c].x, acc.x);
                acc.y = fmaf(wgt[p][c], v[p][c].y, acc.y);
                acc.z = fmaf(wgt[p][c], v[p][c].z, acc.z);
                acc.w = fmaf(wgt[p][c], v[p][c].w, acc.w);
            }
    }

    // out: (bs,Q,nh,8) f32x4; streamed once -> nontemporal store
    __builtin_nontemporal_store(acc, &out4[lg * (DD / 4) + lane]);
}

extern "C" void kernel_launch(void* const* d_in, const int* in_sizes, int n_in,
                              void* d_out, int out_size, void* d_ws, size_t ws_size,
                              hipStream_t stream) {
    const f32x4* value4 = (const f32x4*)d_in[0];
    const f32x4* locv   = (const f32x4*)d_in[2];
    const f32x4* awv    = (const f32x4*)d_in[3];
    f32x4*       out4   = (f32x4*)d_out;

    msda_fwd_kernel<<<NWG, 256, 0, stream>>>(value4, locv, awv, out4);
}

// Round 10
// 141.720 us; speedup vs baseline: 6.0954x; 6.0954x over previous
//
#include <hip/hip_runtime.h>

// Multi-scale deformable attention (Deformable-DETR), forward. All shapes static:
// value: (2, 13294, 8, 32) f32 | loc: (2,13294,8,4,4,2) f32 | aw: (2,13294,8,4,4) f32
// out:   (2, 13294, 256) f32 (head-major channels)
//
// NOTES (hard-won):
// - XCD blockIdx swizzle BANNED: reproducibly trips post-timing re-validation (R2,R5).
// - Source-level load batching + sched_barrier(0) spills to scratch (R7: 864 us).
// - R8/R9 core dumps were NOT the inline asm: both had an OOB value base
//   ((b*KK*NH+h)*KSTR instead of *(DD/4)) -> device fault. Fixed here.

#define BS 2
#define NH 8
#define DD 32
#define QQ 13294
#define KK 13294
#define QH 6647            // QQ/2: chain B handles q + QH
#define LPG 8              // lanes per group; each lane holds 4 channels (f32x4)
#define GPB 32             // groups (pairs) per 256-thread block
#define NPAIR (BS * NH * QH)          // 106352 query-pairs
#define NWG ((NPAIR + GPB - 1) / GPB) // 3324 blocks (last block 16/32 active)
#define KSTR (NH * DD / 4) // 64 f32x4 between consecutive keys

typedef float f32x4 __attribute__((ext_vector_type(4)));

// One pyramid level for one query chain: 4 samples x 4 corners -> acc.
__device__ __forceinline__ void level_chain(const f32x4* __restrict__ vbase,
                                            const f32x4 lv0, const f32x4 lv1,
                                            const f32x4 wv,
                                            const int H, const int W, const int start,
                                            f32x4& acc)
{
    const float fH = (float)H, fW = (float)W;
    #pragma unroll
    for (int p = 0; p < 4; ++p) {
        const f32x4 lvp = (p < 2) ? lv0 : lv1;
        const float lx = lvp[(p & 1) * 2 + 0];
        const float ly = lvp[(p & 1) * 2 + 1];
        const float w  = wv[p];

        // align_corners=False, padding zeros: x = loc_x*W - 0.5
        const float x = lx * fW - 0.5f;
        const float y = ly * fH - 0.5f;
        const float x0f = floorf(x), y0f = floorf(y);
        const float dx = x - x0f, dy = y - y0f;
        const int x0 = (int)x0f, y0 = (int)y0f;
        const int x1 = x0 + 1,  y1 = y0 + 1;

        const float mx0 = ((unsigned)x0 < (unsigned)W) ? 1.0f : 0.0f;
        const float mx1 = ((unsigned)x1 < (unsigned)W) ? 1.0f : 0.0f;
        const float my0 = ((unsigned)y0 < (unsigned)H) ? 1.0f : 0.0f;
        const float my1 = ((unsigned)y1 < (unsigned)H) ? 1.0f : 0.0f;

        const int cx0 = min(max(x0, 0), W - 1);
        const int cx1 = min(max(x1, 0), W - 1);
        const int cy0 = min(max(y0, 0), H - 1);
        const int cy1 = min(max(y1, 0), H - 1);

        const float w00 = (1.0f - dx) * (1.0f - dy) * w * mx0 * my0;
        const float w01 = dx * (1.0f - dy) * w * mx1 * my0;
        const float w10 = (1.0f - dx) * dy * w * mx0 * my1;
        const float w11 = dx * dy * w * mx1 * my1;

        const int r0 = start + cy0 * W;
        const int r1 = start + cy1 * W;
        const f32x4 v00 = vbase[(size_t)(r0 + cx0) * KSTR];
        const f32x4 v01 = vbase[(size_t)(r0 + cx1) * KSTR];
        const f32x4 v10 = vbase[(size_t)(r1 + cx0) * KSTR];
        const f32x4 v11 = vbase[(size_t)(r1 + cx1) * KSTR];

        acc.x = fmaf(w00, v00.x, acc.x);
        acc.y = fmaf(w00, v00.y, acc.y);
        acc.z = fmaf(w00, v00.z, acc.z);
        acc.w = fmaf(w00, v00.w, acc.w);
        acc.x = fmaf(w01, v01.x, acc.x);
        acc.y = fmaf(w01, v01.y, acc.y);
        acc.z = fmaf(w01, v01.z, acc.z);
        acc.w = fmaf(w01, v01.w, acc.w);
        acc.x = fmaf(w10, v10.x, acc.x);
        acc.y = fmaf(w10, v10.y, acc.y);
        acc.z = fmaf(w10, v10.z, acc.z);
        acc.w = fmaf(w10, v10.w, acc.w);
        acc.x = fmaf(w11, v11.x, acc.x);
        acc.y = fmaf(w11, v11.y, acc.y);
        acc.z = fmaf(w11, v11.z, acc.z);
        acc.w = fmaf(w11, v11.w, acc.w);
    }
}

__global__ __launch_bounds__(256, 4) void msda_fwd_kernel(
    const f32x4* __restrict__ value4,  // (bs,K,nh,8) f32x4
    const f32x4* __restrict__ locv,    // (bs,Q,nh,L,P,2) viewed as f32x4[...][8]
    const f32x4* __restrict__ awv,     // (bs,Q,nh,L,P)   viewed as f32x4[...][4]
    f32x4*       __restrict__ out4)    // (bs,Q,nh,8) f32x4
{
    constexpr int Hs[4]     = {100, 50, 25, 13};
    constexpr int Ws[4]     = {100, 50, 25, 13};
    constexpr int starts[4] = {0, 10000, 12500, 13125};

    const int pair = blockIdx.x * GPB + (threadIdx.x >> 3);
    const int lane = threadIdx.x & (LPG - 1);
    if (pair >= NPAIR) return;

    // pair = bh * QH + qh; chain A: q = qh, chain B: q = qh + QH (same b,h slab)
    const int qh = pair % QH;
    const int bh = pair / QH;
    const int h  = bh % NH;
    const int b  = bh / NH;

    // loc/aw group index: (b*QQ + q)*NH + h
    const size_t giA = ((size_t)(b * QQ + qh) * NH + h);
    const size_t giB = ((size_t)(b * QQ + qh + QH) * NH + h);

    const f32x4* lpA = locv + giA * 8;
    const f32x4* wpA = awv  + giA * 4;
    const f32x4* lpB = locv + giB * 8;
    const f32x4* wpB = awv  + giB * 4;

    // value base for (b, k=0, h, lane): ((b*KK+0)*NH + h)*(DD/4) + lane.
    // Base scales by DD/4=8 (NOT KSTR=64 -- that was the R8/R9 OOB fault).
    const f32x4* vbase = value4 + ((size_t)b * KK * NH + h) * (DD / 4) + lane;

    f32x4 accA = {0.f, 0.f, 0.f, 0.f};
    f32x4 accB = {0.f, 0.f, 0.f, 0.f};

    #pragma unroll
    for (int l = 0; l < 4; ++l) {
        const f32x4 lvA0 = __builtin_nontemporal_load(&lpA[2 * l + 0]);
        const f32x4 lvA1 = __builtin_nontemporal_load(&lpA[2 * l + 1]);
        const f32x4 wvA  = __builtin_nontemporal_load(&wpA[l]);
        const f32x4 lvB0 = __builtin_nontemporal_load(&lpB[2 * l + 0]);
        const f32x4 lvB1 = __builtin_nontemporal_load(&lpB[2 * l + 1]);
        const f32x4 wvB  = __builtin_nontemporal_load(&wpB[l]);

        // Two fully independent chains: scheduler can overlap B's loads with
        // A's load-use stalls (and vice versa) without holding many lives.
        level_chain(vbase, lvA0, lvA1, wvA, Hs[l], Ws[l], starts[l], accA);
        level_chain(vbase, lvB0, lvB1, wvB, Hs[l], Ws[l], starts[l], accB);
    }

    __builtin_nontemporal_store(accA, &out4[giA * (DD / 4) + lane]);
    __builtin_nontemporal_store(accB, &out4[giB * (DD / 4) + lane]);
}

extern "C" void kernel_launch(void* const* d_in, const int* in_sizes, int n_in,
                              void* d_out, int out_size, void* d_ws, size_t ws_size,
                              hipStream_t stream) {
    const f32x4* value4 = (const f32x4*)d_in[0];
    const f32x4* locv   = (const f32x4*)d_in[2];
    const f32x4* awv    = (const f32x4*)d_in[3];
    f32x4*       out4   = (f32x4*)d_out;

    msda_fwd_kernel<<<NWG, 256, 0, stream>>>(value4, locv, awv, out4);
}

// Round 12
// 141.099 us; speedup vs baseline: 6.1222x; 1.0044x over previous
//
#include <hip/hip_runtime.h>

// Multi-scale deformable attention (Deformable-DETR), forward. All shapes static:
// value: (2, 13294, 8, 32) f32 | loc: (2,13294,8,4,4,2) f32 | aw: (2,13294,8,4,4) f32
// out:   (2, 13294, 256) f32 (head-major channels)
//
// NOTES (hard-won):
// - XCD blockIdx swizzle BANNED: reproducibly trips post-timing re-validation (R2,R5).
// - Source-level load batching + sched_barrier(0) spills to scratch (R7: 864 us).
// - Inline-asm load pipeline: regalloc copies asm outputs before the counted
//   wait -> garbage (R11). Intra-wave MLP is a dead end on this compiler.
// - Two-chain per-thread MLP: compiler re-serializes (R10, -8%).
// THIS ROUND: kill the latency instead. value (b,K,h,D) puts slab lines at
// stride 1024B -> only 1/8 of L2 sets usable -> 512KB effective < 1.7MB slab
// -> thrash (FETCH 7x value size). Repack to (b,h,K,D) in d_ws first.

#define BS 2
#define NH 8
#define DD 32
#define QQ 13294
#define KK 13294
#define LPG 8    // lanes per group; each lane holds 4 channels (f32x4)
#define GPB 32   // groups per 256-thread block
#define NWG 6647 // BS*NH*QQ / GPB, exact (no tail)
#define NV4 (BS * KK * NH * (DD / 4))   // 1,701,632 f32x4 in value
#define RWG (NV4 / 256)                 // 6647 repack blocks, exact

typedef float f32x4 __attribute__((ext_vector_type(4)));

// ---------------- Kernel 1: repack value (b,K,h,D) -> (b,h,K,D) ----------------
__global__ __launch_bounds__(256) void msda_repack_kernel(
    const f32x4* __restrict__ value4,   // (b,K,h,8)
    f32x4*       __restrict__ packed4)  // (b,h,K,8)
{
    const int idx = blockIdx.x * 256 + threadIdx.x;  // linear over (b,k,h,d4)
    const int d4 = idx & 7;
    const int t  = idx >> 3;
    const int h  = t % NH;
    const int bk = t / NH;
    const int k  = bk % KK;
    const int b  = bk / KK;
    const f32x4 v = __builtin_nontemporal_load(&value4[idx]);  // read once, linear
    packed4[(((size_t)(b * NH + h) * KK) + k) * 8 + d4] = v;   // keep in L2 for K2
}

// ---------------- Kernel 2: gather from packed (or direct fallback) -----------
template <int KSTRIDE>
__global__ __launch_bounds__(256, 4) void msda_fwd_kernel(
    const f32x4* __restrict__ val4,    // packed: (b,h,K,8) | direct: (b,K,h,8)
    const f32x4* __restrict__ locv,    // (bs,Q,nh,L,P,2) viewed as f32x4[...][8]
    const f32x4* __restrict__ awv,     // (bs,Q,nh,L,P)   viewed as f32x4[...][4]
    f32x4*       __restrict__ out4)    // (bs,Q,nh,8) f32x4
{
    constexpr int Hs[4]     = {100, 50, 25, 13};
    constexpr int Ws[4]     = {100, 50, 25, 13};
    constexpr int starts[4] = {0, 10000, 12500, 13125};

    const int gid  = blockIdx.x * GPB + (threadIdx.x >> 3);  // (b,h,q)-ordered
    const int lane = threadIdx.x & (LPG - 1);

    const int q  = gid % QQ;
    const int bh = gid / QQ;
    const int h  = bh % NH;
    const int b  = bh / NH;

    const size_t lg = (size_t)(b * QQ + q) * NH + h;
    const f32x4* lp = locv + lg * 8;
    const f32x4* wp = awv  + lg * 4;

    // Base for (b, k=0, h, lane). Packed: slab is contiguous; key stride 8 f32x4.
    // Direct: base scales by DD/4=8 (NOT the key stride 64 -- R8/R9 OOB lesson).
    const f32x4* vbase = (KSTRIDE == 8)
        ? val4 + ((size_t)(b * NH + h) * KK) * 8 + lane
        : val4 + ((size_t)b * KK * NH + h) * (DD / 4) + lane;

    f32x4 acc = {0.f, 0.f, 0.f, 0.f};

    #pragma unroll
    for (int l = 0; l < 4; ++l) {
        const int H = Hs[l], W = Ws[l];
        const float fH = (float)H, fW = (float)W;
        const f32x4 lv0 = __builtin_nontemporal_load(&lp[2 * l + 0]);
        const f32x4 lv1 = __builtin_nontemporal_load(&lp[2 * l + 1]);
        const f32x4 wvv = __builtin_nontemporal_load(&wp[l]);

        #pragma unroll
        for (int p = 0; p < 4; ++p) {
            const f32x4 lvp = (p < 2) ? lv0 : lv1;
            const float lx = lvp[(p & 1) * 2 + 0];
            const float ly = lvp[(p & 1) * 2 + 1];
            const float w  = wvv[p];

            // align_corners=False, padding zeros: x = loc_x*W - 0.5
            const float x = lx * fW - 0.5f;
            const float y = ly * fH - 0.5f;
            const float x0f = floorf(x), y0f = floorf(y);
            const float dx = x - x0f, dy = y - y0f;
            const int x0 = (int)x0f, y0 = (int)y0f;
            const int x1 = x0 + 1,  y1 = y0 + 1;

            const float mx0 = ((unsigned)x0 < (unsigned)W) ? 1.0f : 0.0f;
            const float mx1 = ((unsigned)x1 < (unsigned)W) ? 1.0f : 0.0f;
            const float my0 = ((unsigned)y0 < (unsigned)H) ? 1.0f : 0.0f;
            const float my1 = ((unsigned)y1 < (unsigned)H) ? 1.0f : 0.0f;

            const int cx0 = min(max(x0, 0), W - 1);
            const int cx1 = min(max(x1, 0), W - 1);
            const int cy0 = min(max(y0, 0), H - 1);
            const int cy1 = min(max(y1, 0), H - 1);

            const float w00 = (1.0f - dx) * (1.0f - dy) * w * mx0 * my0;
            const float w01 = dx * (1.0f - dy) * w * mx1 * my0;
            const float w10 = (1.0f - dx) * dy * w * mx0 * my1;
            const float w11 = dx * dy * w * mx1 * my1;

            const int r0 = starts[l] + cy0 * W;
            const int r1 = starts[l] + cy1 * W;
            const f32x4 v00 = vbase[(size_t)(r0 + cx0) * KSTRIDE];
            const f32x4 v01 = vbase[(size_t)(r0 + cx1) * KSTRIDE];
            const f32x4 v10 = vbase[(size_t)(r1 + cx0) * KSTRIDE];
            const f32x4 v11 = vbase[(size_t)(r1 + cx1) * KSTRIDE];

            acc.x = fmaf(w00, v00.x, acc.x);
            acc.y = fmaf(w00, v00.y, acc.y);
            acc.z = fmaf(w00, v00.z, acc.z);
            acc.w = fmaf(w00, v00.w, acc.w);
            acc.x = fmaf(w01, v01.x, acc.x);
            acc.y = fmaf(w01, v01.y, acc.y);
            acc.z = fmaf(w01, v01.z, acc.z);
            acc.w = fmaf(w01, v01.w, acc.w);
            acc.x = fmaf(w10, v10.x, acc.x);
            acc.y = fmaf(w10, v10.y, acc.y);
            acc.z = fmaf(w10, v10.z, acc.z);
            acc.w = fmaf(w10, v10.w, acc.w);
            acc.x = fmaf(w11, v11.x, acc.x);
            acc.y = fmaf(w11, v11.y, acc.y);
            acc.z = fmaf(w11, v11.z, acc.z);
            acc.w = fmaf(w11, v11.w, acc.w);
        }
    }

    // out streamed once -> nontemporal store
    __builtin_nontemporal_store(acc, &out4[lg * (DD / 4) + lane]);
}

extern "C" void kernel_launch(void* const* d_in, const int* in_sizes, int n_in,
                              void* d_out, int out_size, void* d_ws, size_t ws_size,
                              hipStream_t stream) {
    const f32x4* value4 = (const f32x4*)d_in[0];
    const f32x4* locv   = (const f32x4*)d_in[2];
    const f32x4* awv    = (const f32x4*)d_in[3];
    f32x4*       out4   = (f32x4*)d_out;

    const size_t need = (size_t)NV4 * sizeof(f32x4);  // 27.2 MB
    if (ws_size >= need) {
        f32x4* packed4 = (f32x4*)d_ws;
        msda_repack_kernel<<<RWG, 256, 0, stream>>>(value4, packed4);
        msda_fwd_kernel<8><<<NWG, 256, 0, stream>>>(packed4, locv, awv, out4);
    } else {
        msda_fwd_kernel<NH * DD / 4><<<NWG, 256, 0, stream>>>(value4, locv, awv, out4);
    }
}